// Round 7
// baseline (101.958 us; speedup 1.0000x reference)
//
#include <hip/hip_runtime.h>

#define NDOM 8
#define TT   32      // tile dim
#define KDIM 1024    // feature dim (harness-fixed)
#define RPAD 1040    // LDS row stride: 1024 + 16 pad -> 4-bank skew per row
#define BMAX 4096    // batch (harness-fixed)
#define GGRID 512    // k_gram grid (2 blocks/CU, single residency round)

typedef float f32x4 __attribute__((ext_vector_type(4)));

__device__ inline void gload16(const void* g, void* l) {
    __builtin_amdgcn_global_load_lds(
        (const __attribute__((address_space(1))) unsigned int*)g,
        (__attribute__((address_space(3))) unsigned int*)l, 16, 0, 0);
}

// ------------------------------------------------------------------ prep ----
// Block 0: label bucketing (ballot/popc) -> perm, dom_off; zeroes bar.
// Blocks 1..512: fp32 -> fp8(e4m3) convert in ORIGINAL order (8 rows each)
// + row norms. Dispatch boundary makes all of it visible to k_gram.
__global__ __launch_bounds__(256) void k_prep(
    const float* __restrict__ F, const int* __restrict__ labels, int B,
    unsigned char* __restrict__ Fb, float* __restrict__ sq,
    int* __restrict__ perm, int* __restrict__ dom_off, unsigned* __restrict__ bar) {
    const int t = threadIdx.x, lane = t & 63, wv = t >> 6;

    if (blockIdx.x == 0) {
        __shared__ int lab[BMAX];
        __shared__ unsigned wcnt[4][NDOM];
        for (int i = t; i < BMAX; i += 256) lab[i] = (i < B) ? labels[i] : -1;
        __syncthreads();

        int nch = (B + 63) >> 6;
        int cpw = (nch + 3) >> 2;
        int c0 = wv * cpw, c1 = min(c0 + cpw, nch);
        unsigned long long below = (1ull << lane) - 1ull;

        unsigned cnt[NDOM];
#pragma unroll
        for (int d = 0; d < NDOM; ++d) cnt[d] = 0;
        for (int c = c0; c < c1; ++c) {
            int d = lab[c * 64 + lane];
#pragma unroll
            for (int dd = 0; dd < NDOM; ++dd)
                cnt[dd] += (unsigned)__popcll(__ballot(d == dd));
        }
        if (lane == 0)
#pragma unroll
            for (int dd = 0; dd < NDOM; ++dd) wcnt[wv][dd] = cnt[dd];
        __syncthreads();

        unsigned offs[NDOM + 1];
        offs[0] = 0;
#pragma unroll
        for (int dd = 0; dd < NDOM; ++dd)
            offs[dd + 1] = offs[dd] + wcnt[0][dd] + wcnt[1][dd] + wcnt[2][dd] + wcnt[3][dd];
        if (t <= NDOM) dom_off[t] = (int)offs[t];
        if (t == 0) *bar = 0u;

        unsigned run[NDOM];
#pragma unroll
        for (int dd = 0; dd < NDOM; ++dd) {
            unsigned base = offs[dd];
            for (int w = 0; w < 4; ++w)
                if (w < wv) base += wcnt[w][dd];
            run[dd] = base;
        }
        for (int c = c0; c < c1; ++c) {
            int i = c * 64 + lane;
            int d = lab[i];
            int pos = -1;
#pragma unroll
            for (int dd = 0; dd < NDOM; ++dd) {
                unsigned long long m = __ballot(d == dd);
                if (d == dd) pos = (int)run[dd] + __popcll(m & below);
                run[dd] += (unsigned)__popcll(m);
            }
            if (i < B) perm[pos] = i;
        }
        return;
    }

    int i0 = (int)(blockIdx.x - 1) * 8;
    for (int j = wv; j < 8; j += 4) {     // 2 rows per wave
        int row = i0 + j;
        if (row >= B) break;
        const float4* srow = (const float4*)(F + (size_t)row * KDIM);
        int* drow = (int*)(Fb + (size_t)row * KDIM);
        float ss = 0.f;
#pragma unroll
        for (int it = 0; it < 4; ++it) {
            float4 v = srow[it * 64 + lane];
            ss += v.x * v.x + v.y * v.y + v.z * v.z + v.w * v.w;
            int p = __builtin_amdgcn_cvt_pk_fp8_f32(v.x, v.y, 0, false);
            p = __builtin_amdgcn_cvt_pk_fp8_f32(v.z, v.w, p, true);
            drow[it * 64 + lane] = p;
        }
#pragma unroll
        for (int s = 32; s > 0; s >>= 1) ss += __shfl_xor(ss, s);
        if (lane == 0) sq[row] = ss;
    }
}

// ------------------------------------------------------------------ gram ----
// R6 core (proven) + next-tile perm/sq register prefetch overlapped with the
// staging drain + last-arriving-block finalize (no contended per-tile device
// atomics; completion counter is 512 spread increments).
__global__ __launch_bounds__(256) void k_gram(
    const unsigned char* __restrict__ Fb, const float* __restrict__ sq,
    const int* __restrict__ perm, const int* __restrict__ dom_off,
    float* __restrict__ part, unsigned* __restrict__ bar,
    float* __restrict__ out) {
    __shared__ __align__(16) unsigned char lA[TT * RPAD];  // 32.5 KB
    __shared__ __align__(16) unsigned char lB[TT * RPAD];  // 32.5 KB
    __shared__ int s_p[64];
    __shared__ float s_sq[64];
    __shared__ int s_offs[NDOM + 1], s_ts[NDOM + 1];
    __shared__ float s_ps[NDOM];
    __shared__ float red[NDOM][33];
    __shared__ unsigned s_last;

    const int t = threadIdx.x, lane = t & 63, wv = t >> 6;
    const int m16 = lane & 15, quad = lane >> 4;
    const int wm = (wv & 1) * 16, wn = (wv >> 1) * 16;

    if (t == 0) {
        int T = 0;
        for (int d = 0; d < NDOM; ++d) {
            int o0 = dom_off[d], o1 = dom_off[d + 1];
            s_offs[d] = o0;
            s_ts[d] = T;
            int n = o1 - o0;
            int nt = (n + TT - 1) / TT;
            T += nt * (nt + 1) / 2;
        }
        s_offs[NDOM] = dom_off[NDOM];
        s_ts[NDOM] = T;
    }
    if (t < NDOM) s_ps[t] = 0.f;
    __syncthreads();
    const int T = s_ts[NDOM];

    // tile decode (LDS tables are read-only after init)
    auto decode = [&](int tile, int& off, int& n, int& tr, int& tc,
                      int& dom, bool& diag) {
        dom = 0;
        while (tile >= s_ts[dom + 1]) ++dom;
        off = s_offs[dom];
        n = s_offs[dom + 1] - off;
        int nt = (n + TT - 1) / TT;
        int rel = tile - s_ts[dom];
        int ty = 0, rem = rel;
        while (rem >= nt - ty) { rem -= nt - ty; ++ty; }
        int tx = ty + rem;
        tr = ty * TT;
        tc = tx * TT;
        diag = (ty == tx);
    };

    int pf_p = 0;
    float pf_sq = 0.f;
    auto prefetch = [&](int tile) {
        if (tile < T && t < 64) {
            int off, n, tr, tc, dom;
            bool dg;
            decode(tile, off, n, tr, tc, dom, dg);
            int r = (t < 32) ? min(tr + t, n - 1) : min(tc + (t - 32), n - 1);
            pf_p = perm[off + r];
            pf_sq = sq[pf_p];
        }
    };
    prefetch(blockIdx.x);

    for (int tile = blockIdx.x; tile < T; tile += gridDim.x) {
        int off, n, tr, tc, dom;
        bool diag;
        decode(tile, off, n, tr, tc, dom, diag);

        if (t < 64) { s_p[t] = pf_p; s_sq[t] = pf_sq; }
        __syncthreads();

        // staging: 1 instr/row, lanes linear -> coalesced 1 KB per instr
#pragma unroll
        for (int j = 0; j < 16; ++j) {
            int r = wv * 16 + j;          // 0..63: A rows 0..31, B rows 32..63
            if (r < 32) {
                const unsigned char* g = Fb + (size_t)s_p[r] * KDIM + lane * 16;
                gload16(g, lA + r * RPAD);
            } else if (!diag) {
                const unsigned char* g = Fb + (size_t)s_p[r] * KDIM + lane * 16;
                gload16(g, lB + (r - 32) * RPAD);
            }
        }
        prefetch(tile + (int)gridDim.x);  // overlaps the staging drain below
        __syncthreads();                  // single vmcnt drain per tile

        const unsigned char* Bbuf = diag ? lA : lB;
        const unsigned char* pa = lA + (wm + m16) * RPAD + quad * 8;
        const unsigned char* pb = Bbuf + (wn + m16) * RPAD + quad * 8;
        f32x4 ac0 = (f32x4){0.f, 0.f, 0.f, 0.f};
        f32x4 ac1 = (f32x4){0.f, 0.f, 0.f, 0.f};
#pragma unroll
        for (int ks = 0; ks < 32; ks += 2) {
            long a0 = *(const long*)(pa + ks * 32);
            long b0 = *(const long*)(pb + ks * 32);
            long a1 = *(const long*)(pa + ks * 32 + 32);
            long b1 = *(const long*)(pb + ks * 32 + 32);
            ac0 = __builtin_amdgcn_mfma_f32_16x16x32_fp8_fp8(a0, b0, ac0, 0, 0, 0);
            ac1 = __builtin_amdgcn_mfma_f32_16x16x32_fp8_fp8(a1, b1, ac1, 0, 0, 0);
        }

        float local = 0.f;
        int lr0 = wm + quad * 4;
        int lc = wn + m16;
        int pc = tc + lc;
        if (pc < n) {
            float sb = s_sq[32 + lc];
#pragma unroll
            for (int r = 0; r < 4; ++r) {
                int pr = tr + lr0 + r;
                if (pr < n) {
                    float val;
                    if (pr == pc) {
                        val = 1.0f;       // exact: dist(i,i) == 0
                    } else {
                        float d2 = s_sq[lr0 + r] + sb - 2.0f * (ac0[r] + ac1[r]);
                        d2 = fmaxf(d2, 0.f);
                        val = fmaxf(1.0f - sqrtf(d2), 0.f);
                    }
                    local += val;
                }
            }
        }
        if (!diag) local *= 2.f;
#pragma unroll
        for (int s = 32; s > 0; s >>= 1) local += __shfl_xor(local, s);
        if (lane == 0) atomicAdd(&s_ps[dom], local);  // LDS atomic: uncontended
        __syncthreads();                  // LDS reuse fence before next tile
    }

    // ---- export block-private sums (device-scope stores), then finalize ----
    if (t < NDOM)
        __hip_atomic_store(&part[blockIdx.x * NDOM + t], s_ps[t],
                           __ATOMIC_RELAXED, __HIP_MEMORY_SCOPE_AGENT);
    __syncthreads();
    if (t == 0) {
        __threadfence();                  // release
        unsigned old = atomicAdd(bar, 1u);
        s_last = (old == (unsigned)gridDim.x - 1) ? 1u : 0u;
    }
    __syncthreads();
    if (s_last) {
        if (t == 0) __threadfence();      // acquire
        __syncthreads();
        int d = t & 7, ch = t >> 3;       // 32 chunks x 8 domains
        float s = 0.f;
        for (int b = ch; b < GGRID; b += 32)
            s += __hip_atomic_load(&part[b * NDOM + d], __ATOMIC_RELAXED,
                                   __HIP_MEMORY_SCOPE_AGENT);
        red[d][ch] = s;
        __syncthreads();
        if (t == 0) {
            float acc = 0.f;
            int v = 0;
            for (int dd = 0; dd < NDOM; ++dd) {
                int n = s_offs[dd + 1] - s_offs[dd];
                if (n > 1) {
                    float ps = 0.f;
                    for (int c = 0; c < 32; ++c) ps += red[dd][c];
                    acc += ps / ((float)n * (float)n);
                    ++v;
                }
            }
            out[0] = (v > 0) ? acc / (float)v : 0.f;
        }
    }
}

// ---------------------------------------------------------------- launch ----
extern "C" void kernel_launch(void* const* d_in, const int* in_sizes, int n_in,
                              void* d_out, int out_size, void* d_ws, size_t ws_size,
                              hipStream_t stream) {
    const float* F = (const float*)d_in[0];
    const int* labels = (const int*)d_in[1];
    int B = in_sizes[1];                 // 4096

    char* ws = (char*)d_ws;
    unsigned char* Fb = (unsigned char*)ws;
    float* sq = (float*)(ws + (size_t)BMAX * KDIM);
    int* perm = (int*)(ws + (size_t)BMAX * KDIM + BMAX * 4);
    int* dom_off = (int*)(ws + (size_t)BMAX * KDIM + BMAX * 8);
    unsigned* bar = (unsigned*)(ws + (size_t)BMAX * KDIM + BMAX * 8 + 128);
    float* part = (float*)(ws + (size_t)BMAX * KDIM + BMAX * 8 + 256);

    int ncv = (B + 7) / 8;
    k_prep<<<ncv + 1, 256, 0, stream>>>(F, labels, B, Fb, sq, perm, dom_off, bar);
    k_gram<<<GGRID, 256, 0, stream>>>(Fb, sq, perm, dom_off, part, bar, (float*)d_out);
}

// Round 9
// 97.782 us; speedup vs baseline: 1.0427x; 1.0427x over previous
//
#include <hip/hip_runtime.h>

#define NDOM 8
#define TT   64      // tile dim (64x64 upper-triangle tiles)
#define KDIM 1024    // feature dim (harness-fixed)
#define RPAD 1040    // LDS row stride: 1024 + 16 pad -> 4-bank skew per row
#define BMAX 4096    // batch (harness-fixed)
#define GGRID 512    // k_gram grid

typedef float f32x4 __attribute__((ext_vector_type(4)));

__device__ inline void gload16(const void* g, void* l) {
    __builtin_amdgcn_global_load_lds(
        (const __attribute__((address_space(1))) unsigned int*)g,
        (__attribute__((address_space(3))) unsigned int*)l, 16, 0, 0);
}

// ------------------------------------------------------------------ prep ----
// Block 0: label bucketing (ballot/popc) -> perm, dom_off.
// Blocks 1..: fp32 -> fp8(e4m3) convert in ORIGINAL order (16 rows/block).
__global__ __launch_bounds__(256) void k_prep(
    const float* __restrict__ F, const int* __restrict__ labels, int B,
    unsigned char* __restrict__ Fb, float* __restrict__ sq,
    int* __restrict__ perm, int* __restrict__ dom_off) {
    const int t = threadIdx.x, lane = t & 63, wv = t >> 6;

    if (blockIdx.x == 0) {
        __shared__ int lab[BMAX];
        __shared__ unsigned wcnt[4][NDOM];
        for (int i = t; i < BMAX; i += 256) lab[i] = (i < B) ? labels[i] : -1;
        __syncthreads();

        int nch = (B + 63) >> 6;
        int cpw = (nch + 3) >> 2;
        int c0 = wv * cpw, c1 = min(c0 + cpw, nch);
        unsigned long long below = (1ull << lane) - 1ull;

        unsigned cnt[NDOM];
#pragma unroll
        for (int d = 0; d < NDOM; ++d) cnt[d] = 0;
        for (int c = c0; c < c1; ++c) {
            int d = lab[c * 64 + lane];
#pragma unroll
            for (int dd = 0; dd < NDOM; ++dd)
                cnt[dd] += (unsigned)__popcll(__ballot(d == dd));
        }
        if (lane == 0)
#pragma unroll
            for (int dd = 0; dd < NDOM; ++dd) wcnt[wv][dd] = cnt[dd];
        __syncthreads();

        unsigned offs[NDOM + 1];
        offs[0] = 0;
#pragma unroll
        for (int dd = 0; dd < NDOM; ++dd)
            offs[dd + 1] = offs[dd] + wcnt[0][dd] + wcnt[1][dd] + wcnt[2][dd] + wcnt[3][dd];
        if (t <= NDOM) dom_off[t] = (int)offs[t];

        unsigned run[NDOM];
#pragma unroll
        for (int dd = 0; dd < NDOM; ++dd) {
            unsigned base = offs[dd];
            for (int w = 0; w < 4; ++w)
                if (w < wv) base += wcnt[w][dd];
            run[dd] = base;
        }
        for (int c = c0; c < c1; ++c) {
            int i = c * 64 + lane;
            int d = lab[i];
            int pos = -1;
#pragma unroll
            for (int dd = 0; dd < NDOM; ++dd) {
                unsigned long long m = __ballot(d == dd);
                if (d == dd) pos = (int)run[dd] + __popcll(m & below);
                run[dd] += (unsigned)__popcll(m);
            }
            if (i < B) perm[pos] = i;
        }
        return;
    }

    int i0 = (int)(blockIdx.x - 1) * 16;
    for (int j = wv; j < 16; j += 4) {
        int row = i0 + j;
        if (row >= B) break;
        const float4* srow = (const float4*)(F + (size_t)row * KDIM);
        int* drow = (int*)(Fb + (size_t)row * KDIM);
        float ss = 0.f;
#pragma unroll
        for (int it = 0; it < 4; ++it) {
            float4 v = srow[it * 64 + lane];
            ss += v.x * v.x + v.y * v.y + v.z * v.z + v.w * v.w;
            int p = __builtin_amdgcn_cvt_pk_fp8_f32(v.x, v.y, 0, false);
            p = __builtin_amdgcn_cvt_pk_fp8_f32(v.z, v.w, p, true);
            drow[it * 64 + lane] = p;
        }
#pragma unroll
        for (int s = 32; s > 0; s >>= 1) ss += __shfl_xor(ss, s);
        if (lane == 0) sq[row] = ss;
    }
}

// ------------------------------------------------------------------ gram ----
// 64x64 upper-triangle fp8 tiles, full-K LDS-resident. ~330 tiles total ->
// ~1 tile/block at grid 512 (1 block/CU: 133 KB LDS). 4 waves in 2x2; each
// wave 32x32 = 2x2 subtiles, 4 MFMA + 4 ds_read_b64 per ks (1:1). Exit via
// block-private partial stores (R6-proven; no contended device atomics).
// R9 fix vs R8: epilogue accumulator select is an explicit register ternary
// (R8 used a GNU compound-literal array -> dangling pointer UB -> garbage).
__global__ __launch_bounds__(256) void k_gram(
    const unsigned char* __restrict__ Fb, const float* __restrict__ sq,
    const int* __restrict__ perm, const int* __restrict__ dom_off,
    float* __restrict__ part) {
    __shared__ __align__(16) unsigned char lA[TT * RPAD];  // 65 KB
    __shared__ __align__(16) unsigned char lB[TT * RPAD];  // 65 KB
    __shared__ int s_p[128];
    __shared__ float s_sq[128];
    __shared__ int s_offs[NDOM + 1], s_ts[NDOM + 1];
    __shared__ float s_ps[NDOM];

    const int t = threadIdx.x, lane = t & 63, wv = t >> 6;
    const int m16 = lane & 15, quad = lane >> 4;
    const int wm = (wv & 1) * 32, wn = (wv >> 1) * 32;

    if (t == 0) {
        int T = 0;
        for (int d = 0; d < NDOM; ++d) {
            int o0 = dom_off[d], o1 = dom_off[d + 1];
            s_offs[d] = o0;
            s_ts[d] = T;
            int n = o1 - o0;
            int nt = (n + TT - 1) / TT;
            T += nt * (nt + 1) / 2;
        }
        s_offs[NDOM] = dom_off[NDOM];
        s_ts[NDOM] = T;
    }
    if (t < NDOM) s_ps[t] = 0.f;
    __syncthreads();
    const int T = s_ts[NDOM];

    for (int tile = blockIdx.x; tile < T; tile += gridDim.x) {
        int dom = 0;
        while (tile >= s_ts[dom + 1]) ++dom;
        int off = s_offs[dom], n = s_offs[dom + 1] - off;
        int nt = (n + TT - 1) / TT;
        int rel = tile - s_ts[dom];
        int ty = 0, rem = rel;
        while (rem >= nt - ty) { rem -= nt - ty; ++ty; }
        int tx = ty + rem;
        int tr = ty * TT, tc = tx * TT;
        bool diag = (ty == tx);

        // rows at s_p[0..63], cols at s_p[64..127]
        if (t < 128) {
            int r = (t < 64) ? min(tr + t, n - 1) : min(tc + (t - 64), n - 1);
            int p = perm[off + r];
            s_p[t] = p;
            s_sq[t] = sq[p];
        }
        __syncthreads();

        // staging: 1 instr/row, lanes linear (coalesced 1 KB/instr)
#pragma unroll
        for (int j = 0; j < 16; ++j) {
            int r = wv * 16 + j;          // 0..63
            gload16(Fb + (size_t)s_p[r] * KDIM + lane * 16, lA + r * RPAD);
            if (!diag)
                gload16(Fb + (size_t)s_p[64 + r] * KDIM + lane * 16, lB + r * RPAD);
        }
        __syncthreads();   // single vmcnt drain per tile

        const unsigned char* Bb = diag ? lA : lB;
        const unsigned char* pa0 = lA + (wm + m16) * RPAD + quad * 8;
        const unsigned char* pa1 = lA + (wm + 16 + m16) * RPAD + quad * 8;
        const unsigned char* pb0 = Bb + (wn + m16) * RPAD + quad * 8;
        const unsigned char* pb1 = Bb + (wn + 16 + m16) * RPAD + quad * 8;
        f32x4 a00 = (f32x4){0.f, 0.f, 0.f, 0.f};
        f32x4 a01 = (f32x4){0.f, 0.f, 0.f, 0.f};
        f32x4 a10 = (f32x4){0.f, 0.f, 0.f, 0.f};
        f32x4 a11 = (f32x4){0.f, 0.f, 0.f, 0.f};
#pragma unroll
        for (int ks = 0; ks < 32; ++ks) {
            long av0 = *(const long*)(pa0 + ks * 32);
            long av1 = *(const long*)(pa1 + ks * 32);
            long bv0 = *(const long*)(pb0 + ks * 32);
            long bv1 = *(const long*)(pb1 + ks * 32);
            a00 = __builtin_amdgcn_mfma_f32_16x16x32_fp8_fp8(av0, bv0, a00, 0, 0, 0);
            a01 = __builtin_amdgcn_mfma_f32_16x16x32_fp8_fp8(av0, bv1, a01, 0, 0, 0);
            a10 = __builtin_amdgcn_mfma_f32_16x16x32_fp8_fp8(av1, bv0, a10, 0, 0, 0);
            a11 = __builtin_amdgcn_mfma_f32_16x16x32_fp8_fp8(av1, bv1, a11, 0, 0, 0);
        }

        // epilogue: subtile (im,in): C[row=quad*4+r][col=m16]
        float local = 0.f;
#pragma unroll
        for (int im = 0; im < 2; ++im) {
            int lr0 = wm + im * 16 + quad * 4;
#pragma unroll
            for (int in = 0; in < 2; ++in) {
                f32x4 av = (im == 0) ? ((in == 0) ? a00 : a01)
                                     : ((in == 0) ? a10 : a11);
                int lc = wn + in * 16 + m16;
                int pc = tc + lc;
                if (pc >= n) continue;
                float sb = s_sq[64 + lc];
#pragma unroll
                for (int r = 0; r < 4; ++r) {
                    int pr = tr + lr0 + r;
                    if (pr < n) {
                        float val;
                        if (pr == pc) {
                            val = 1.0f;   // exact: dist(i,i) == 0
                        } else {
                            float d2 = s_sq[lr0 + r] + sb - 2.0f * av[r];
                            d2 = fmaxf(d2, 0.f);
                            val = fmaxf(1.0f - sqrtf(d2), 0.f);
                        }
                        local += val;
                    }
                }
            }
        }
        if (!diag) local *= 2.f;
#pragma unroll
        for (int s = 32; s > 0; s >>= 1) local += __shfl_xor(local, s);
        if (lane == 0) atomicAdd(&s_ps[dom], local);   // LDS atomic, uncontended
        __syncthreads();   // LDS reuse fence (only matters if block gets 2 tiles)
    }

    __syncthreads();
    if (t < NDOM) part[blockIdx.x * NDOM + t] = s_ps[t];  // private slot store
}

// -------------------------------------------------------------- finalize ----
__global__ __launch_bounds__(256) void k_final(
    const float* __restrict__ part, const int* __restrict__ dom_off,
    float* __restrict__ out) {
    __shared__ float red[8][32];
    int t = threadIdx.x;
    int d = t & 7, ch = t >> 3;           // 32 chunks x 8 domains
    float s = 0.f;
    for (int b = ch; b < GGRID; b += 32) s += part[b * NDOM + d];
    red[d][ch] = s;
    __syncthreads();
    if (t == 0) {
        float acc = 0.f;
        int v = 0;
        for (int dd = 0; dd < NDOM; ++dd) {
            int n = dom_off[dd + 1] - dom_off[dd];
            if (n > 1) {
                float ps = 0.f;
                for (int c = 0; c < 32; ++c) ps += red[dd][c];
                acc += ps / ((float)n * (float)n);
                ++v;
            }
        }
        out[0] = (v > 0) ? acc / (float)v : 0.f;
    }
}

// ---------------------------------------------------------------- launch ----
extern "C" void kernel_launch(void* const* d_in, const int* in_sizes, int n_in,
                              void* d_out, int out_size, void* d_ws, size_t ws_size,
                              hipStream_t stream) {
    const float* F = (const float*)d_in[0];
    const int* labels = (const int*)d_in[1];
    int B = in_sizes[1];                 // 4096

    char* ws = (char*)d_ws;
    unsigned char* Fb = (unsigned char*)ws;
    float* sq = (float*)(ws + (size_t)BMAX * KDIM);
    int* perm = (int*)(ws + (size_t)BMAX * KDIM + BMAX * 4);
    int* dom_off = (int*)(ws + (size_t)BMAX * KDIM + BMAX * 8);
    float* part = (float*)(ws + (size_t)BMAX * KDIM + BMAX * 8 + 256);

    int ncv = (B + 15) / 16;
    k_prep<<<ncv + 1, 256, 0, stream>>>(F, labels, B, Fb, sq, perm, dom_off);
    k_gram<<<GGRID, 256, 0, stream>>>(Fb, sq, perm, dom_off, part);
    k_final<<<1, 256, 0, stream>>>(part, dom_off, (float*)d_out);
}